// Round 4
// baseline (663.131 us; speedup 1.0000x reference)
//
#include <hip/hip_runtime.h>
#include <math.h>

// Problem constants (from setup_inputs in the reference)
constexpr int NSTEP = 730;
constexpr int NGRID = 2000;
constexpr int MU    = 16;
constexpr int NOUT  = 500;
#define PRECS_F 1e-5f

// fast 2^x / log2(x) on the SFU (v_exp_f32 / v_log_f32)
#define EXP2F(v) __builtin_amdgcn_exp2f(v)
#define LOG2F(v) __builtin_amdgcn_logf(v)

// ---------------------------------------------------------------------------
// Kernel 1: per-(grid,mu) sequential HBV state machine.
// 32000 threads, block=64 (1 wave), 500 blocks, state in registers.
// Grid is only ~0.5 waves/SIMD -> latency-bound. R3 showed VGPR_Count=64:
// the scheduler optimizes for 8-waves/SIMD occupancy by default and sank the
// D=10 prefetch next to its uses. amdgpu_waves_per_eu(1,1) pins the occupancy
// target to what the grid actually delivers, freeing ~512 VGPRs so all D*6
// in-flight load results stay live.
// ---------------------------------------------------------------------------
constexpr int D = 10; // 730 % 10 == 0

__global__ __attribute__((amdgpu_flat_work_group_size(64, 64),
                          amdgpu_waves_per_eu(1, 1)))
void hbv_scan(
    const float* __restrict__ x,      // [NSTEP][NGRID][3]
    const float* __restrict__ params, // [NSTEP][NGRID][3][MU]
    const float* __restrict__ wl,     // [NGRID][13][MU]
    const float* __restrict__ Ai,     // [NGRID]
    const float* __restrict__ Acb,    // [NGRID]
    float* __restrict__ qw)           // [NSTEP][NGRID]
{
  const int tid = blockIdx.x * 64 + threadIdx.x; // 0..31999 exactly
  const int g   = tid >> 4;
  const int mu  = tid & 15;

  // --- time-invariant waterloss params (SCA2 transform) ---
  const float* w = wl + (g * 13) * MU + mu;
#define LDP(i, lo, hi) ((lo) + w[(i) * MU] * ((hi) - (lo)))
  const float parFC    = LDP(0, 50.f, 1000.f);
  const float parK1    = LDP(1, 0.01f, 0.5f);
  const float parK2    = LDP(2, 0.001f, 0.2f);
  const float parLP    = LDP(3, 0.2f, 1.0f);
  const float parPERC  = LDP(4, 0.f, 10.f);
  const float parUZL   = LDP(5, 0.f, 100.f);
  const float parTT    = LDP(6, -2.5f, 2.5f);
  const float parCFMAX = LDP(7, 0.5f, 10.f);
  const float parCFR   = LDP(8, 0.f, 0.1f);
  const float parCWH   = LDP(9, 0.f, 0.2f);
  const float parC     = LDP(10, 0.f, 1.f);
  const float parTR    = LDP(11, 0.f, 20.f);
  const float parAc    = LDP(12, 0.f, 2500.f);
#undef LDP

  const float ac = Acb[g];
  float rf;
  if (ac < 2500.f) {
    rf = fminf(fmaxf((ac - parAc) / 1000.f, -1.f), 1.f) * parTR;
  } else {
    rf = expf(fmaxf(-(ac - 2500.f) / 50.f, -10.f)) * parTR; // upper clip 0 implied (arg<=0)
  }
  const float aig     = Ai[g] * (1.f / 16.f); // fold mean(mu) and Ai
  const float invFC   = 1.f / parFC;
  const float invLPFC = 1.f / (parLP * parFC);
  const float cfrmax  = parCFR * parCFMAX;

  float SP = 0.001f, MW = 0.001f, SM = 0.001f, SUZ = 0.001f, SLZ = 0.001f;

  const float* pptr = params + g * (3 * MU) + mu;
  const float* xptr = x + g * 3;
  constexpr int PSTR = NGRID * 3 * MU; // 96000
  constexpr int XSTR = NGRID * 3;      // 6000

  // prefetch pipeline registers (D*6 = 60 VGPRs of in-flight loads)
  float pb0[D], pb1[D], pb2[D], xb0[D], xb1[D], xb2[D];
#pragma unroll
  for (int d = 0; d < D; ++d) {
    pb0[d] = pptr[d * PSTR];
    pb1[d] = pptr[d * PSTR + MU];
    pb2[d] = pptr[d * PSTR + 2 * MU];
    xb0[d] = xptr[d * XSTR];
    xb1[d] = xptr[d * XSTR + 1];
    xb2[d] = xptr[d * XSTR + 2];
  }

  for (int tb = 0; tb < NSTEP; tb += D) {
#pragma unroll
    for (int d = 0; d < D; ++d) {
      const int t = tb + d;
      const float c0 = pb0[d], c1 = pb1[d], c2 = pb2[d];
      const float Pt = xb0[d], Tt = xb1[d], Et = xb2[d];

      // issue prefetch for step t+D (clamped; always issues -> no branch,
      // pipeline stays full; redundant tail loads are harmless/cached)
      int tn = t + D;
      tn = (tn < NSTEP) ? tn : (NSTEP - 1);
      pb0[d] = pptr[tn * PSTR];
      pb1[d] = pptr[tn * PSTR + MU];
      pb2[d] = pptr[tn * PSTR + 2 * MU];
      xb0[d] = xptr[tn * XSTR];
      xb1[d] = xptr[tn * XSTR + 1];
      xb2[d] = xptr[tn * XSTR + 2];

      // time-varying params (SCA1 transform)
      const float parBETA   = fmaf(c0, 5.0f, 1.0f);
      const float parK0     = fmaf(c1, 0.85f, 0.05f);
      const float parBETAET = fmaf(c2, 4.7f, 0.3f);

      const float dT    = Tt - parTT;
      const bool  isR   = (Tt >= parTT);
      const float RAIN  = isR ? Pt : 0.f;
      const float SNOW  = isR ? 0.f : Pt;
      SP += SNOW;
      const float melt = fminf(fmaxf(parCFMAX * dT, 0.f), SP);
      MW += melt;
      SP -= melt;
      const float refr = fminf(fmaxf(cfrmax * (-dT), 0.f), MW);
      SP += refr;
      MW -= refr;
      const float tosoil = fmaxf(MW - parCWH * SP, 0.f);
      MW -= tosoil;
      // soil_wetness = clip((SM/FC)^BETA, 0, 1); base > 0 always (SM >= PRECS)
      const float sw = fminf(EXP2F(parBETA * LOG2F(SM * invFC)), 1.f);
      const float rt = RAIN + tosoil;
      const float rech = rt * sw;
      SM = SM + rt - rech;
      const float excess = fmaxf(SM - parFC, 0.f);
      SM -= excess;
      const float ef    = fminf(EXP2F(parBETAET * LOG2F(SM * invLPFC)), 1.f);
      const float ETact = fminf(SM, Et * ef);
      SM = fmaxf(SM - ETact, PRECS_F);
      const float cap = fminf(SLZ, parC * SLZ * (1.f - fminf(SM * invFC, 1.f)));
      SM  = fmaxf(SM + cap, PRECS_F);
      SLZ = fmaxf(SLZ - cap, PRECS_F);
      SUZ = SUZ + rech + excess;
      const float PERC = fminf(SUZ, parPERC);
      SUZ -= PERC;
      const float Q0 = parK0 * fmaxf(SUZ - parUZL, 0.f);
      SUZ -= Q0;
      const float Q1 = parK1 * SUZ;
      SUZ -= Q1;
      SLZ += PERC;
      SLZ = fmaxf(SLZ + rf, 0.f);
      const float Q2 = parK2 * SLZ;
      SLZ -= Q2;

      // mean over the 16 mu lanes (off the carry chain)
      float q = Q0 + Q1 + Q2;
      q += __shfl_xor(q, 1);
      q += __shfl_xor(q, 2);
      q += __shfl_xor(q, 4);
      q += __shfl_xor(q, 8);
      if (mu == 0) qw[t * NGRID + g] = q * aig;
    }
  }
}

// ---------------------------------------------------------------------------
// Kernel 2: out[t][j] = sum_g qw[t][g] * idx[g][j]   (730 x 500 x 2000)
// Block = (TT=10 timesteps) x (125 float4 j-quads); g range [g0, g0+gcount)
// processed in chunks of GCHUNK staged to LDS. NO ATOMICS in any mode:
//   partials path: gcount=GCH, writes partial plane pb[blockIdx.y], reduced
//   by hbv_reduce.  fallback path: gridDim.y=1, gcount=NGRID, direct write.
// (R3's 376us mystery gap was almost certainly the atomicAdd fallback running
//  because ws_size < 29.2MB; GSPLIT=8 needs only 17.5MB and fallback is now
//  atomic-free.)
// ---------------------------------------------------------------------------
constexpr int TT     = 10;  // 730 % 10 == 0 -> 73 t-blocks, no tail
constexpr int GSPLIT = 8;
constexpr int GCH    = NGRID / GSPLIT; // 250
constexpr int GCHUNK = 250;
constexpr int PF     = 4;
constexpr int NQ     = NOUT / 4;       // 125 j-quads

__global__ __launch_bounds__(128, 1) void hbv_mm(
    const float* __restrict__ qw,   // [NSTEP][NGRID]
    const float* __restrict__ idxm, // [NGRID][NOUT]
    float* __restrict__ dst,        // partials: [gridDim.y][NSTEP][NOUT]; or out
    int gcount)
{
  __shared__ float qt[GCHUNK][12]; // row stride 48B -> aligned float4 reads, 2-way-free banks

  const int jq = threadIdx.x; // 0..127, active j-quads < 125
  const int t0 = blockIdx.x * TT;
  const int gbase = blockIdx.y * gcount;

  const int jql = (jq < NQ) ? jq : (NQ - 1);
  const float4* idx4 = (const float4*)idxm;

  float4 acc[TT];
#pragma unroll
  for (int i = 0; i < TT; ++i) acc[i] = make_float4(0.f, 0.f, 0.f, 0.f);

#define FMA4(A, S, V) A.x = fmaf(S, V.x, A.x); A.y = fmaf(S, V.y, A.y); \
                      A.z = fmaf(S, V.z, A.z); A.w = fmaf(S, V.w, A.w)

  for (int c0 = 0; c0 < gcount; c0 += GCHUNK) {
    const int g0 = gbase + c0;
    __syncthreads();
    // stage transposed qw tile: qt[gg][i] = qw[t0+i][g0+gg]
    for (int e = threadIdx.x; e < TT * GCHUNK; e += 128) {
      const int i = e / GCHUNK, gg = e - i * GCHUNK;
      qt[gg][i] = qw[(t0 + i) * NGRID + (g0 + gg)];
    }
    __syncthreads();

    float4 ivb[PF];
#pragma unroll
    for (int p = 0; p < PF; ++p) ivb[p] = idx4[(g0 + p) * NQ + jql];

    for (int gg = 0; gg < GCHUNK; ++gg) {
      const int s = gg & (PF - 1);
      const float4 iv = ivb[s];
      int gn = gg + PF;
      gn = (gn < GCHUNK) ? gn : (GCHUNK - 1);
      ivb[s] = idx4[(g0 + gn) * NQ + jql]; // prefetch PF iters ahead

      const float4 qA = *(const float4*)&qt[gg][0]; // broadcast LDS reads
      const float4 qB = *(const float4*)&qt[gg][4];
      const float2 qC = *(const float2*)&qt[gg][8];
      FMA4(acc[0], qA.x, iv); FMA4(acc[1], qA.y, iv);
      FMA4(acc[2], qA.z, iv); FMA4(acc[3], qA.w, iv);
      FMA4(acc[4], qB.x, iv); FMA4(acc[5], qB.y, iv);
      FMA4(acc[6], qB.z, iv); FMA4(acc[7], qB.w, iv);
      FMA4(acc[8], qC.x, iv); FMA4(acc[9], qC.y, iv);
    }
  }
#undef FMA4

  if (jq < NQ) {
    float* base = dst + (size_t)blockIdx.y * (NSTEP * NOUT);
#pragma unroll
    for (int i = 0; i < TT; ++i)
      *(float4*)(base + (t0 + i) * NOUT + jq * 4) = acc[i];
  }
}

// Reduce the GSPLIT partials into d_out (float4 per thread).
__global__ __launch_bounds__(256) void hbv_reduce(
    const float* __restrict__ pb, // [GSPLIT][NSTEP][NOUT]
    float* __restrict__ out)      // [NSTEP*NOUT]
{
  const int q = blockIdx.x * 256 + threadIdx.x; // float4 index
  constexpr int NQTOT = NSTEP * NOUT / 4;       // 91250
  if (q >= NQTOT) return;
  const float4* p4 = (const float4*)pb;
  float4 s = p4[q];
#pragma unroll
  for (int k = 1; k < GSPLIT; ++k) {
    const float4 v = p4[(size_t)k * NQTOT + q];
    s.x += v.x; s.y += v.y; s.z += v.z; s.w += v.w;
  }
  ((float4*)out)[q] = s;
}

// ---------------------------------------------------------------------------
extern "C" void kernel_launch(void* const* d_in, const int* in_sizes, int n_in,
                              void* d_out, int out_size, void* d_ws, size_t ws_size,
                              hipStream_t stream) {
  const float* x      = (const float*)d_in[0]; // (730,2000,3)
  const float* params = (const float*)d_in[1]; // (730,2000,3,16)
  const float* wl     = (const float*)d_in[2]; // (2000,13,16)
  const float* Ai     = (const float*)d_in[3]; // (2000,)
  const float* Ac     = (const float*)d_in[4]; // (2000,)
  const float* idxm   = (const float*)d_in[5]; // (2000,500)
  // d_in[6] = mu (scalar 16), hardcoded

  float* out = (float*)d_out; // (730,500,1)
  float* qw  = (float*)d_ws;  // 730*2000 floats = 5.84 MB

  const size_t qw_bytes = (size_t)NSTEP * NGRID * sizeof(float);
  const size_t pb_elems = (size_t)GSPLIT * NSTEP * NOUT;
  const bool use_partials = ws_size >= qw_bytes + pb_elems * sizeof(float); // 17.5 MB
  float* pb = (float*)((char*)d_ws + qw_bytes);

  hbv_scan<<<dim3((NGRID * MU) / 64), dim3(64), 0, stream>>>(x, params, wl, Ai, Ac, qw);

  if (use_partials) {
    hbv_mm<<<dim3(NSTEP / TT, GSPLIT), dim3(128), 0, stream>>>(qw, idxm, pb, GCH);
    hbv_reduce<<<dim3((NSTEP * NOUT / 4 + 255) / 256), dim3(256), 0, stream>>>(pb, out);
  } else {
    // atomic-free fallback: one block owns each (t-tile, j-quad) fully
    hbv_mm<<<dim3(NSTEP / TT, 1), dim3(128), 0, stream>>>(qw, idxm, out, NGRID);
  }
}

// Round 5
// 588.427 us; speedup vs baseline: 1.1270x; 1.1270x over previous
//
#include <hip/hip_runtime.h>
#include <math.h>

// Problem constants (from setup_inputs in the reference)
constexpr int NSTEP = 730;
constexpr int NGRID = 2000;
constexpr int MU    = 16;
constexpr int NOUT  = 500;
#define PRECS_F 1e-5f

// fast 2^x / log2(x) on the SFU (v_exp_f32 / v_log_f32)
#define EXP2F(v) __builtin_amdgcn_exp2f(v)
#define LOG2F(v) __builtin_amdgcn_logf(v)

// DPP row-rotate move (VALU-speed cross-lane within 16-lane rows; no LDS pipe)
template <int CTRL>
__device__ __forceinline__ float dpp_rot(float x) {
  int r = __builtin_amdgcn_update_dpp(0, __builtin_bit_cast(int, x),
                                      CTRL, 0xf, 0xf, true);
  return __builtin_bit_cast(float, r);
}

// ---------------------------------------------------------------------------
// Kernel 1: per-(grid,mu) sequential HBV state machine.
// 32000 threads, block=64 (1 wave), 500 blocks, state in registers.
// R4 post-mortem: VGPR 64->132 changed nothing (838 cyc/step invariant to
// prefetch depth) -> limiter was the per-step __shfl_xor x4 mean-reduction
// (ds_swizzle = dependent LDS round trips, ~480 cyc with 1 wave/SIMD).
// Replaced with DPP row_ror rotate-reduce: 4 dependent VALU adds (~16 cyc).
// ---------------------------------------------------------------------------
constexpr int D = 10; // 730 % 10 == 0

__global__ __attribute__((amdgpu_flat_work_group_size(64, 64),
                          amdgpu_waves_per_eu(1, 1)))
void hbv_scan(
    const float* __restrict__ x,      // [NSTEP][NGRID][3]
    const float* __restrict__ params, // [NSTEP][NGRID][3][MU]
    const float* __restrict__ wl,     // [NGRID][13][MU]
    const float* __restrict__ Ai,     // [NGRID]
    const float* __restrict__ Acb,    // [NGRID]
    float* __restrict__ qw)           // [NSTEP][NGRID]
{
  const int tid = blockIdx.x * 64 + threadIdx.x; // 0..31999 exactly
  const int g   = tid >> 4;
  const int mu  = tid & 15;

  // --- time-invariant waterloss params (SCA2 transform) ---
  const float* w = wl + (g * 13) * MU + mu;
#define LDP(i, lo, hi) ((lo) + w[(i) * MU] * ((hi) - (lo)))
  const float parFC    = LDP(0, 50.f, 1000.f);
  const float parK1    = LDP(1, 0.01f, 0.5f);
  const float parK2    = LDP(2, 0.001f, 0.2f);
  const float parLP    = LDP(3, 0.2f, 1.0f);
  const float parPERC  = LDP(4, 0.f, 10.f);
  const float parUZL   = LDP(5, 0.f, 100.f);
  const float parTT    = LDP(6, -2.5f, 2.5f);
  const float parCFMAX = LDP(7, 0.5f, 10.f);
  const float parCFR   = LDP(8, 0.f, 0.1f);
  const float parCWH   = LDP(9, 0.f, 0.2f);
  const float parC     = LDP(10, 0.f, 1.f);
  const float parTR    = LDP(11, 0.f, 20.f);
  const float parAc    = LDP(12, 0.f, 2500.f);
#undef LDP

  const float ac = Acb[g];
  float rf;
  if (ac < 2500.f) {
    rf = fminf(fmaxf((ac - parAc) / 1000.f, -1.f), 1.f) * parTR;
  } else {
    rf = expf(fmaxf(-(ac - 2500.f) / 50.f, -10.f)) * parTR; // upper clip 0 implied (arg<=0)
  }
  const float aig     = Ai[g] * (1.f / 16.f); // fold mean(mu) and Ai
  const float invFC   = 1.f / parFC;
  const float invLPFC = 1.f / (parLP * parFC);
  const float cfrmax  = parCFR * parCFMAX;

  float SP = 0.001f, MW = 0.001f, SM = 0.001f, SUZ = 0.001f, SLZ = 0.001f;

  const float* pptr = params + g * (3 * MU) + mu;
  const float* xptr = x + g * 3;
  constexpr int PSTR = NGRID * 3 * MU; // 96000
  constexpr int XSTR = NGRID * 3;      // 6000

  // prefetch pipeline registers (D*6 = 60 VGPRs of in-flight loads)
  float pb0[D], pb1[D], pb2[D], xb0[D], xb1[D], xb2[D];
#pragma unroll
  for (int d = 0; d < D; ++d) {
    pb0[d] = pptr[d * PSTR];
    pb1[d] = pptr[d * PSTR + MU];
    pb2[d] = pptr[d * PSTR + 2 * MU];
    xb0[d] = xptr[d * XSTR];
    xb1[d] = xptr[d * XSTR + 1];
    xb2[d] = xptr[d * XSTR + 2];
  }

  for (int tb = 0; tb < NSTEP; tb += D) {
#pragma unroll
    for (int d = 0; d < D; ++d) {
      const int t = tb + d;
      const float c0 = pb0[d], c1 = pb1[d], c2 = pb2[d];
      const float Pt = xb0[d], Tt = xb1[d], Et = xb2[d];

      // issue prefetch for step t+D (clamped; always issues)
      int tn = t + D;
      tn = (tn < NSTEP) ? tn : (NSTEP - 1);
      pb0[d] = pptr[tn * PSTR];
      pb1[d] = pptr[tn * PSTR + MU];
      pb2[d] = pptr[tn * PSTR + 2 * MU];
      xb0[d] = xptr[tn * XSTR];
      xb1[d] = xptr[tn * XSTR + 1];
      xb2[d] = xptr[tn * XSTR + 2];

      // time-varying params (SCA1 transform)
      const float parBETA   = fmaf(c0, 5.0f, 1.0f);
      const float parK0     = fmaf(c1, 0.85f, 0.05f);
      const float parBETAET = fmaf(c2, 4.7f, 0.3f);

      const float dT    = Tt - parTT;
      const bool  isR   = (Tt >= parTT);
      const float RAIN  = isR ? Pt : 0.f;
      const float SNOW  = isR ? 0.f : Pt;
      SP += SNOW;
      const float melt = fminf(fmaxf(parCFMAX * dT, 0.f), SP);
      MW += melt;
      SP -= melt;
      const float refr = fminf(fmaxf(cfrmax * (-dT), 0.f), MW);
      SP += refr;
      MW -= refr;
      const float tosoil = fmaxf(MW - parCWH * SP, 0.f);
      MW -= tosoil;
      // soil_wetness = clip((SM/FC)^BETA, 0, 1); base > 0 always (SM >= PRECS)
      const float sw = fminf(EXP2F(parBETA * LOG2F(SM * invFC)), 1.f);
      const float rt = RAIN + tosoil;
      const float rech = rt * sw;
      SM = SM + rt - rech;
      const float excess = fmaxf(SM - parFC, 0.f);
      SM -= excess;
      const float ef    = fminf(EXP2F(parBETAET * LOG2F(SM * invLPFC)), 1.f);
      const float ETact = fminf(SM, Et * ef);
      SM = fmaxf(SM - ETact, PRECS_F);
      const float cap = fminf(SLZ, parC * SLZ * (1.f - fminf(SM * invFC, 1.f)));
      SM  = fmaxf(SM + cap, PRECS_F);
      SLZ = fmaxf(SLZ - cap, PRECS_F);
      SUZ = SUZ + rech + excess;
      const float PERC = fminf(SUZ, parPERC);
      SUZ -= PERC;
      const float Q0 = parK0 * fmaxf(SUZ - parUZL, 0.f);
      SUZ -= Q0;
      const float Q1 = parK1 * SUZ;
      SUZ -= Q1;
      SLZ += PERC;
      SLZ = fmaxf(SLZ + rf, 0.f);
      const float Q2 = parK2 * SLZ;
      SLZ -= Q2;

      // mean over the 16 mu lanes: DPP rotate-reduce (pure VALU, no LDS pipe)
      float q = Q0 + Q1 + Q2;
      q += dpp_rot<0x121>(q); // row_ror:1
      q += dpp_rot<0x122>(q); // row_ror:2
      q += dpp_rot<0x124>(q); // row_ror:4
      q += dpp_rot<0x128>(q); // row_ror:8  -> every lane holds row sum
      if (mu == 0) qw[t * NGRID + g] = q * aig;
    }
  }
}

// ---------------------------------------------------------------------------
// Kernel 2a (partials path, needs 11.7MB extra ws): as R4.
// ---------------------------------------------------------------------------
constexpr int TT     = 10;  // 730 % 10 == 0
constexpr int GSPLIT = 8;
constexpr int GCH    = NGRID / GSPLIT; // 250
constexpr int PF     = 4;
constexpr int NQ     = NOUT / 4;       // 125 j-quads

#define FMA4(A, S, V) A.x = fmaf(S, V.x, A.x); A.y = fmaf(S, V.y, A.y); \
                      A.z = fmaf(S, V.z, A.z); A.w = fmaf(S, V.w, A.w)

__global__ __launch_bounds__(128, 1) void hbv_mm(
    const float* __restrict__ qw,   // [NSTEP][NGRID]
    const float* __restrict__ idxm, // [NGRID][NOUT]
    float* __restrict__ dst)        // partials [GSPLIT][NSTEP][NOUT]
{
  __shared__ float qt[GCH][12];

  const int jq = threadIdx.x;
  const int t0 = blockIdx.x * TT;
  const int g0 = blockIdx.y * GCH;
  const int jql = (jq < NQ) ? jq : (NQ - 1);
  const float4* idx4 = (const float4*)idxm;

  float4 acc[TT];
#pragma unroll
  for (int i = 0; i < TT; ++i) acc[i] = make_float4(0.f, 0.f, 0.f, 0.f);

  for (int e = threadIdx.x; e < TT * GCH; e += 128) {
    const int i = e / GCH, gg = e - i * GCH;
    qt[gg][i] = qw[(t0 + i) * NGRID + (g0 + gg)];
  }
  __syncthreads();

  float4 ivb[PF];
#pragma unroll
  for (int p = 0; p < PF; ++p) ivb[p] = idx4[(g0 + p) * NQ + jql];

  for (int gg = 0; gg < GCH; ++gg) {
    const int s = gg & (PF - 1);
    const float4 iv = ivb[s];
    int gn = gg + PF;
    gn = (gn < GCH) ? gn : (GCH - 1);
    ivb[s] = idx4[(g0 + gn) * NQ + jql];

    const float4 qA = *(const float4*)&qt[gg][0];
    const float4 qB = *(const float4*)&qt[gg][4];
    const float2 qC = *(const float2*)&qt[gg][8];
    FMA4(acc[0], qA.x, iv); FMA4(acc[1], qA.y, iv);
    FMA4(acc[2], qA.z, iv); FMA4(acc[3], qA.w, iv);
    FMA4(acc[4], qB.x, iv); FMA4(acc[5], qB.y, iv);
    FMA4(acc[6], qB.z, iv); FMA4(acc[7], qB.w, iv);
    FMA4(acc[8], qC.x, iv); FMA4(acc[9], qC.y, iv);
  }

  if (jq < NQ) {
    float* base = dst + (size_t)blockIdx.y * (NSTEP * NOUT);
#pragma unroll
    for (int i = 0; i < TT; ++i)
      *(float4*)(base + (t0 + i) * NOUT + jq * 4) = acc[i];
  }
}

__global__ __launch_bounds__(256) void hbv_reduce(
    const float* __restrict__ pb, float* __restrict__ out)
{
  const int q = blockIdx.x * 256 + threadIdx.x;
  constexpr int NQTOT = NSTEP * NOUT / 4;
  if (q >= NQTOT) return;
  const float4* p4 = (const float4*)pb;
  float4 s = p4[q];
#pragma unroll
  for (int k = 1; k < GSPLIT; ++k) {
    const float4 v = p4[(size_t)k * NQTOT + q];
    s.x += v.x; s.y += v.y; s.z += v.z; s.w += v.w;
  }
  ((float4*)out)[q] = s;
}

// ---------------------------------------------------------------------------
// Kernel 2b (zero-extra-ws path): 146 blocks x 512 threads. 4 g-groups per
// block (500 g each), qw tiles staged in LDS, cross-group reduce in LDS,
// direct float4 stores. No atomics, no partial planes.
// ---------------------------------------------------------------------------
constexpr int TT2   = 5;            // 730 % 5 == 0 -> 146 blocks
constexpr int NWG   = 4;            // g-groups per block
constexpr int GPW   = NGRID / NWG;  // 500
constexpr int CHUNK = 250;

__global__ __launch_bounds__(512, 1) void hbv_mm_block(
    const float* __restrict__ qw,   // [NSTEP][NGRID]
    const float* __restrict__ idxm, // [NGRID][NOUT]
    float* __restrict__ out)        // [NSTEP][NOUT]
{
  __shared__ float qt[NWG][CHUNK][8]; // 32 KB; rows 16B-aligned for float4
  __shared__ float red[512 * 4];      // 8 KB reduce buffer

  const int jq  = threadIdx.x & 127;
  const int grp = threadIdx.x >> 7;   // 0..3
  const int t0  = blockIdx.x * TT2;
  const int jql = (jq < NQ) ? jq : (NQ - 1);
  const float4* idx4 = (const float4*)idxm;

  float4 acc[TT2];
#pragma unroll
  for (int i = 0; i < TT2; ++i) acc[i] = make_float4(0.f, 0.f, 0.f, 0.f);

  for (int c = 0; c < GPW; c += CHUNK) {
    __syncthreads();
    // stage qt[gs][gg][i] = qw[t0+i][gs*GPW + c + gg]  (coalesced in gg)
    for (int e = threadIdx.x; e < NWG * CHUNK * TT2; e += 512) {
      const int gs  = e / (CHUNK * TT2);
      const int rem = e - gs * (CHUNK * TT2);
      const int i   = rem / CHUNK;
      const int gg  = rem - i * CHUNK;
      qt[gs][gg][i] = qw[(t0 + i) * NGRID + gs * GPW + c + gg];
    }
    __syncthreads();

    const int gb = grp * GPW + c;
    float4 ivb[PF];
#pragma unroll
    for (int p = 0; p < PF; ++p) ivb[p] = idx4[(gb + p) * NQ + jql];

    for (int gg = 0; gg < CHUNK; ++gg) {
      const int s = gg & (PF - 1);
      const float4 iv = ivb[s];
      int gn = gg + PF;
      gn = (gn < CHUNK) ? gn : (CHUNK - 1);
      ivb[s] = idx4[(gb + gn) * NQ + jql]; // prefetch PF iters ahead

      const float4 qA = *(const float4*)&qt[grp][gg][0]; // broadcast reads
      const float  qE = qt[grp][gg][4];
      FMA4(acc[0], qA.x, iv); FMA4(acc[1], qA.y, iv);
      FMA4(acc[2], qA.z, iv); FMA4(acc[3], qA.w, iv);
      FMA4(acc[4], qE,   iv);
    }
  }

  // reduce the 4 group partials through LDS, one timestep at a time
  for (int i = 0; i < TT2; ++i) {
    __syncthreads();
    *(float4*)&red[threadIdx.x * 4] = acc[i];
    __syncthreads();
    if (grp == 0 && jq < NQ) {
      float4 s = *(const float4*)&red[jq * 4];
#pragma unroll
      for (int k = 1; k < NWG; ++k) {
        const float4 v = *(const float4*)&red[(jq + 128 * k) * 4];
        s.x += v.x; s.y += v.y; s.z += v.z; s.w += v.w;
      }
      *(float4*)(out + (t0 + i) * NOUT + jq * 4) = s;
    }
  }
}

// ---------------------------------------------------------------------------
extern "C" void kernel_launch(void* const* d_in, const int* in_sizes, int n_in,
                              void* d_out, int out_size, void* d_ws, size_t ws_size,
                              hipStream_t stream) {
  const float* x      = (const float*)d_in[0]; // (730,2000,3)
  const float* params = (const float*)d_in[1]; // (730,2000,3,16)
  const float* wl     = (const float*)d_in[2]; // (2000,13,16)
  const float* Ai     = (const float*)d_in[3]; // (2000,)
  const float* Ac     = (const float*)d_in[4]; // (2000,)
  const float* idxm   = (const float*)d_in[5]; // (2000,500)
  // d_in[6] = mu (scalar 16), hardcoded

  float* out = (float*)d_out; // (730,500,1)
  float* qw  = (float*)d_ws;  // 730*2000 floats = 5.84 MB

  const size_t qw_bytes = (size_t)NSTEP * NGRID * sizeof(float);
  const size_t pb_elems = (size_t)GSPLIT * NSTEP * NOUT;
  const bool use_partials = ws_size >= qw_bytes + pb_elems * sizeof(float); // 17.5 MB
  float* pb = (float*)((char*)d_ws + qw_bytes);

  hbv_scan<<<dim3((NGRID * MU) / 64), dim3(64), 0, stream>>>(x, params, wl, Ai, Ac, qw);

  if (use_partials) {
    hbv_mm<<<dim3(NSTEP / TT, GSPLIT), dim3(128), 0, stream>>>(qw, idxm, pb);
    hbv_reduce<<<dim3((NSTEP * NOUT / 4 + 255) / 256), dim3(256), 0, stream>>>(pb, out);
  } else {
    hbv_mm_block<<<dim3(NSTEP / TT2), dim3(512), 0, stream>>>(qw, idxm, out);
  }
}